// Round 12
// baseline (1678.543 us; speedup 1.0000x reference)
//
#include <hip/hip_runtime.h>

typedef _Float16 half2v __attribute__((ext_vector_type(2)));

#define T_LEN 1024
#define NBATCH 1024
#define HID 20
#define STEPS 4    // timesteps per superstep (one barrier per STEPS steps)

#if defined(__has_builtin)
#if __has_builtin(__builtin_amdgcn_fdot2)
#define HAVE_FDOT2 1
#endif
#endif

__device__ __forceinline__ float fdot2_(half2v a, half2v b, float c) {
#ifdef HAVE_FDOT2
    return __builtin_amdgcn_fdot2(a, b, c, false);
#else
    return c + (float)a[0] * (float)b[0] + (float)a[1] * (float)b[1];
#endif
}

__device__ __forceinline__ half2v pack2(float a, float b) {
    half2v r; r[0] = (_Float16)a; r[1] = (_Float16)b; return r;
}

__device__ __forceinline__ float sigm(float z) {
    return 1.0f / (1.0f + __expf(-z));
}
__device__ __forceinline__ float tanh_s(float z) {
    return 2.0f / (1.0f + __expf(-2.0f * z)) - 1.0f;
}

// Load 20 f16 (one 24-half / 48B row, 16B-aligned) into 10 half2.
__device__ __forceinline__ void load_h20(const _Float16* row, half2v hp[10]) {
    uint4 q0 = *(const uint4*)(row);
    uint4 q1 = *(const uint4*)(row + 8);
    uint2 q2 = *(const uint2*)(row + 16);
    hp[0] = __builtin_bit_cast(half2v, q0.x);
    hp[1] = __builtin_bit_cast(half2v, q0.y);
    hp[2] = __builtin_bit_cast(half2v, q0.z);
    hp[3] = __builtin_bit_cast(half2v, q0.w);
    hp[4] = __builtin_bit_cast(half2v, q1.x);
    hp[5] = __builtin_bit_cast(half2v, q1.y);
    hp[6] = __builtin_bit_cast(half2v, q1.z);
    hp[7] = __builtin_bit_cast(half2v, q1.w);
    hp[8] = __builtin_bit_cast(half2v, q2.x);
    hp[9] = __builtin_bit_cast(half2v, q2.y);
}

// 20-element dot, two independent depth-5 chains.
__device__ __forceinline__ float dot20s(const half2v W[10], const half2v h[10]) {
    float a0 = 0.f, a1 = 0.f;
#pragma unroll
    for (int k = 0; k < 5; ++k) {
        a0 = fdot2_(W[k],     h[k],     a0);
        a1 = fdot2_(W[k + 5], h[k + 5], a1);
    }
    return a0 + a1;
}

// Round-10 structure (best measured: 843 us) at 1 batch/block for 4 blocks/CU
// = 12 waves/CU (3/SIMD) of TLP. Layer-pipelined 3-wave block, 4 gates/lane,
// 4 steps/barrier, depth-8 LDS ring (slot = t & 7). All 4 below-rows +
// ih-dots hoisted to superstep start; own-h dots right after each h write
// (same-wave in-order DS readback).
// Lanes 0..19 active (unit j = lane); lanes 20..63 ride along, never write.
__global__ void __launch_bounds__(192, 3) lstm3_occ(
    const float* __restrict__ x,
    const float* __restrict__ wih0, const float* __restrict__ whh0,
    const float* __restrict__ bih0, const float* __restrict__ bhh0,
    const float* __restrict__ wih1, const float* __restrict__ whh1,
    const float* __restrict__ bih1, const float* __restrict__ bhh1,
    const float* __restrict__ wih2, const float* __restrict__ whh2,
    const float* __restrict__ bih2, const float* __restrict__ bhh2,
    const float* __restrict__ fcw, const float* __restrict__ fcb,
    float* __restrict__ out)
{
    __shared__ __align__(16) float xlds[T_LEN];           // 4 KB staged input
    __shared__ __align__(16) _Float16 rings[3][8][24];    // depth-8 h rings

    const int tid = threadIdx.x;
    const int wv = tid / 64;
    const int lane = tid & 63;
    const int b = blockIdx.x;

    {
        const float4* x4 = (const float4*)(x + (long)b * T_LEN);
        float4* xl4 = (float4*)xlds;
        for (int i = tid; i < T_LEN / 4; i += 192) xl4[i] = x4[i];
        for (int i = tid; i < 3 * 8 * 24; i += 192)
            ((_Float16*)rings)[i] = (_Float16)0.0f;
    }

    const bool act = lane < HID;
    const int j = act ? lane : 0;

    const float* whh = (wv == 0) ? whh0 : (wv == 1) ? whh1 : whh2;
    const float* wih = (wv == 0) ? wih0 : (wv == 1) ? wih1 : wih2;
    const float* bih = (wv == 0) ? bih0 : (wv == 1) ? bih1 : bih2;
    const float* bhh = (wv == 0) ? bhh0 : (wv == 1) ? bhh1 : bhh2;

    // All 4 gate rows (i,f,g,o) of unit j in VGPRs.
    half2v Whh[4][10];
    half2v Wih[4][10];   // waves 1,2
    float bias[4];
    float wx[4] = {0.f, 0.f, 0.f, 0.f};
#pragma unroll
    for (int gt = 0; gt < 4; ++gt) {
        const int r = gt * HID + j;
#pragma unroll
        for (int k4 = 0; k4 < 5; ++k4) {
            float4 v = *(const float4*)(whh + r * HID + 4 * k4);
            Whh[gt][2 * k4]     = pack2(v.x, v.y);
            Whh[gt][2 * k4 + 1] = pack2(v.z, v.w);
        }
        bias[gt] = bih[r] + bhh[r];
        if (wv == 0) {
            wx[gt] = wih[r];  // w_ih0 is (80,1)
        } else {
#pragma unroll
            for (int k4 = 0; k4 < 5; ++k4) {
                float4 v = *(const float4*)(wih + r * HID + 4 * k4);
                Wih[gt][2 * k4]     = pack2(v.x, v.y);
                Wih[gt][2 * k4 + 1] = pack2(v.z, v.w);
            }
        }
    }

    _Float16* const own_base = &rings[wv][0][0];
    const _Float16* const bel_base = (wv > 0) ? &rings[wv - 1][0][0]
                                              : &rings[0][0][0];

    float c = 0.0f;                              // cell state (own unit)
    float oA[4] = {0.f, 0.f, 0.f, 0.f};          // own-h partials (h(-1)=0)

    __syncthreads();

    const int SS = T_LEN / STEPS;  // supersteps per wave
    const int ROW = 24;            // halfs per timestep slot

    for (int s = 0; s < SS + 2; ++s) {
        const int m = s - wv;
        if (m >= 0 && m < SS) {
            const int qb = (m & 1) * (STEPS * ROW);  // quad base (slots 0-3 / 4-7)
            const int t0 = STEPS * m;

            // ---- hoisted pre-gates for ALL 4 steps (independent work) ----
            float pre[STEPS][4];
#pragma unroll
            for (int i = 0; i < STEPS; ++i)
#pragma unroll
                for (int gt = 0; gt < 4; ++gt)
                    pre[i][gt] = bias[gt];
#pragma unroll
            for (int gt = 0; gt < 4; ++gt) pre[0][gt] += oA[gt];

            if (wv == 0) {
#pragma unroll
                for (int i = 0; i < STEPS; ++i) {
                    const float xt = xlds[t0 + i];   // wave-uniform broadcast
#pragma unroll
                    for (int gt = 0; gt < 4; ++gt) pre[i][gt] += wx[gt] * xt;
                }
            } else {
#pragma unroll
                for (int i = 0; i < STEPS; ++i) {
                    half2v hb[10];
                    load_h20(bel_base + qb + i * ROW, hb);
#pragma unroll
                    for (int gt = 0; gt < 4; ++gt)
                        pre[i][gt] += dot20s(Wih[gt], hb);
                }
            }

            // ---- serial chain: 4 steps ----
#pragma unroll
            for (int i = 0; i < STEPS; ++i) {
                float si = sigm(pre[i][0]);
                float sf = sigm(pre[i][1]);
                float tg = tanh_s(pre[i][2]);
                float so = sigm(pre[i][3]);
                c = sf * c + si * tg;
                _Float16* const wp = own_base + qb + i * ROW;
                if (act) wp[j] = (_Float16)(so * tanh_s(c));
                // own-h readback + dots (same-wave in-order DS, no sync)
                half2v ho[10];
                load_h20(wp, ho);
                if (i < STEPS - 1) {
#pragma unroll
                    for (int gt = 0; gt < 4; ++gt)
                        pre[i + 1][gt] += dot20s(Whh[gt], ho);
                } else {
#pragma unroll
                    for (int gt = 0; gt < 4; ++gt)
                        oA[gt] = dot20s(Whh[gt], ho);
                }
            }
        }
        __syncthreads();  // publish this superstep's 4 rows to the wave above
    }

    // FC epilogue: h2(T-1), slot (T_LEN-1)&7 = 7
    if (wv == 2 && lane < 2) {
        float acc = fcb[lane];
        const _Float16* h2 = &rings[2][7][0];
#pragma unroll
        for (int k = 0; k < HID; ++k) {
            acc += fcw[lane * HID + k] * (float)h2[k];
        }
        out[b * 2 + lane] = acc;
    }
}

extern "C" void kernel_launch(void* const* d_in, const int* in_sizes, int n_in,
                              void* d_out, int out_size, void* d_ws, size_t ws_size,
                              hipStream_t stream) {
    const float* x    = (const float*)d_in[0];
    const float* wih0 = (const float*)d_in[1];
    const float* whh0 = (const float*)d_in[2];
    const float* bih0 = (const float*)d_in[3];
    const float* bhh0 = (const float*)d_in[4];
    const float* wih1 = (const float*)d_in[5];
    const float* whh1 = (const float*)d_in[6];
    const float* bih1 = (const float*)d_in[7];
    const float* bhh1 = (const float*)d_in[8];
    const float* wih2 = (const float*)d_in[9];
    const float* whh2 = (const float*)d_in[10];
    const float* bih2 = (const float*)d_in[11];
    const float* bhh2 = (const float*)d_in[12];
    const float* fcw  = (const float*)d_in[13];
    const float* fcb  = (const float*)d_in[14];

    lstm3_occ<<<dim3(NBATCH), dim3(192), 0, stream>>>(
        x, wih0, whh0, bih0, bhh0,
        wih1, whh1, bih1, bhh1,
        wih2, whh2, bih2, bhh2,
        fcw, fcb, (float*)d_out);
}

// Round 13
// 1212.724 us; speedup vs baseline: 1.3841x; 1.3841x over previous
//
#include <hip/hip_runtime.h>

typedef _Float16 f16x8 __attribute__((ext_vector_type(8)));
typedef float f32x4 __attribute__((ext_vector_type(4)));

#define T_LEN 1024
#define NBATCH 1024
#define HID 20
#define NB 16      // batches per block (MFMA N dimension)
#define STEPS 4    // timesteps per superstep (one barrier per STEPS)
#define RROW 40    // ring row stride in halfs (20 h + 12 zero-pad + 8 pad)

__device__ __forceinline__ float sigm(float z) {
    return 1.0f / (1.0f + __expf(-z));
}
__device__ __forceinline__ float tanh_s(float z) {
    return 2.0f / (1.0f + __expf(-2.0f * z)) - 1.0f;
}

// 3-wave layer-pipelined block, 16 batches/block, MFMA gate GEMM.
// Gates GEMM per step per layer: C[80][16] = W'[80][40] * [h_own; h_bel][40][16]
// done as 5 M-tiles of 16 rows x 2 K-MFMAs (own K=32-pad, below K=32-pad).
// Row permutation within tile: rowInTile = 4*unit' + gate, so C-lane
// (a=lane>>4, n=lane&15) reg r holds gate r of unit 4*tile+a, batch n ->
// cell update is lane-local. h ring rows: ring[layer][slot][n*RROW + unit],
// k=20..31 kept zero (MFMA K-pad). B-fragment read: b128 at n*80 + 16*q.
// A-fragments (weights) resident in VGPRs, loaded once.
__global__ void __launch_bounds__(192) lstm3_mfma(
    const float* __restrict__ x,
    const float* __restrict__ wih0, const float* __restrict__ whh0,
    const float* __restrict__ bih0, const float* __restrict__ bhh0,
    const float* __restrict__ wih1, const float* __restrict__ whh1,
    const float* __restrict__ bih1, const float* __restrict__ bhh1,
    const float* __restrict__ wih2, const float* __restrict__ whh2,
    const float* __restrict__ bih2, const float* __restrict__ bhh2,
    const float* __restrict__ fcw, const float* __restrict__ fcb,
    float* __restrict__ out)
{
    __shared__ __align__(16) _Float16 xl[T_LEN * NB];        // x, f16, [t][n] 32KB
    __shared__ __align__(16) _Float16 ring[3][8][NB * RROW]; // h rings   30KB

    const int tid = threadIdx.x;
    const int wv = tid / 64;        // layer index
    const int lane = tid & 63;
    const int n = lane & 15;        // batch column (B/C col)
    const int q = lane >> 4;        // A/B k-octet; C row-group (unit')
    const long b_base = (long)blockIdx.x * NB;

    // stage x (f32 global -> f16 LDS, [t][n]); zero rings
    {
        const float* xg = x + b_base * T_LEN;
        for (int i = tid; i < NB * T_LEN; i += 192) {
            const int bb = i >> 10;          // batch
            const int t = i & (T_LEN - 1);
            xl[t * NB + bb] = (_Float16)xg[i];
        }
        for (int i = tid; i < 3 * 8 * NB * RROW; i += 192)
            ((_Float16*)ring)[i] = (_Float16)0.0f;
    }

    const float* whh = (wv == 0) ? whh0 : (wv == 1) ? whh1 : whh2;
    const float* wih = (wv == 0) ? wih0 : (wv == 1) ? wih1 : wih2;
    const float* bih = (wv == 0) ? bih0 : (wv == 1) ? bih1 : bih2;
    const float* bhh = (wv == 0) ? bhh0 : (wv == 1) ? bhh1 : bhh2;

    // ---- A-fragments (weights), bias (C layout), wx (C layout, wave 0) ----
    f16x8 Ahh[5], Aih[5];
    f32x4 bias4[5], wx4[5];
    {
        const int mrow = lane & 15;          // A-side row-in-tile
        const int gA = mrow & 3;             // gate
        const int uA = mrow >> 2;            // unit'
#pragma unroll
        for (int m = 0; m < 5; ++m) {
            const int RA = gA * HID + 4 * m + uA;   // original W row
#pragma unroll
            for (int j = 0; j < 8; ++j) {
                const int k = 8 * q + j;
                Ahh[m][j] = (k < HID) ? (_Float16)whh[RA * HID + k]
                                      : (_Float16)0.0f;
                Aih[m][j] = (wv > 0 && k < HID) ? (_Float16)wih[RA * HID + k]
                                                : (_Float16)0.0f;
            }
            // C layout: reg r = gate r of unit 4m+q
            f32x4 b4, w4;
#pragma unroll
            for (int r = 0; r < 4; ++r) {
                const int RC = r * HID + 4 * m + q;
                b4[r] = bih[RC] + bhh[RC];
                w4[r] = (wv == 0) ? wih[RC] : 0.0f;  // w_ih0 is (80,1)
            }
            bias4[m] = b4;
            wx4[m] = w4;
        }
    }

    float c5[5] = {0.f, 0.f, 0.f, 0.f, 0.f};  // cell state: unit 4m+q, batch n

    __syncthreads();

    const int SS = T_LEN / STEPS;      // 256 supersteps per wave
    const int SLOT = NB * RROW;        // halfs per ring slot
    const int boff = n * RROW + 8 * q; // B-fragment offset within a slot

    for (int s = 0; s < SS + 2; ++s) {
        const int m = s - wv;
        if (m >= 0 && m < SS) {
            const int t0 = STEPS * m;
            const int qsel = (m & 1) * 4;                 // this quad's slots
            _Float16* const ownQ = &ring[wv][qsel][0];
            const _Float16* const prevOwn =
                &ring[wv][((m & 1) ^ 1) * 4 + 3][0];      // slot of t0-1

            // hoist below B-fragments (4 b128) and x values
            f16x8 bB[STEPS];
            float xv[STEPS];
            if (wv == 0) {
#pragma unroll
                for (int i = 0; i < STEPS; ++i)
                    xv[i] = (float)xl[(t0 + i) * NB + n];
            } else {
                const _Float16* const belQ = &ring[wv - 1][qsel][0];
#pragma unroll
                for (int i = 0; i < STEPS; ++i)
                    bB[i] = *(const f16x8*)(belQ + i * SLOT + boff);
            }

#pragma unroll
            for (int i = 0; i < STEPS; ++i) {
                // own-h(t-1) B-fragment (same-wave in-order DS readback)
                const _Float16* const oSrc =
                    (i == 0) ? prevOwn : (ownQ + (i - 1) * SLOT);
                const f16x8 oB = *(const f16x8*)(oSrc + boff);

                // pre-gates: bias (+x | +below-MFMA) + own-MFMA, 5 tiles
                f32x4 a5[5];
#pragma unroll
                for (int mt = 0; mt < 5; ++mt) {
                    f32x4 a = bias4[mt];
                    if (wv == 0) {
                        a = a + wx4[mt] * xv[i];
                    } else {
                        a = __builtin_amdgcn_mfma_f32_16x16x32_f16(
                            Aih[mt], bB[i], a, 0, 0, 0);
                    }
                    a5[mt] = __builtin_amdgcn_mfma_f32_16x16x32_f16(
                        Ahh[mt], oB, a, 0, 0, 0);
                }

                // activations + cell update (lane-local), h write
                _Float16* const wp = ownQ + i * SLOT;
#pragma unroll
                for (int mt = 0; mt < 5; ++mt) {
                    const f32x4 v = a5[mt];
                    const float si = sigm(v[0]);
                    const float sf = sigm(v[1]);
                    const float tg = tanh_s(v[2]);
                    const float so = sigm(v[3]);
                    c5[mt] = sf * c5[mt] + si * tg;
                    const float hn = so * tanh_s(c5[mt]);
                    wp[n * RROW + 4 * mt + q] = (_Float16)hn;
                }
            }
        }
        __syncthreads();  // publish this superstep's 4 slots to the wave above
    }

    // FC epilogue: h2(T-1) in ring[2][7]
    if (wv == 2 && lane < 2 * NB) {
        const int nn = lane >> 1, o = lane & 1;
        float acc = fcb[o];
        const _Float16* h2 = &ring[2][7][nn * RROW];
#pragma unroll
        for (int k = 0; k < HID; ++k) {
            acc += fcw[o * HID + k] * (float)h2[k];
        }
        out[(b_base + nn) * 2 + o] = acc;
    }
}

extern "C" void kernel_launch(void* const* d_in, const int* in_sizes, int n_in,
                              void* d_out, int out_size, void* d_ws, size_t ws_size,
                              hipStream_t stream) {
    const float* x    = (const float*)d_in[0];
    const float* wih0 = (const float*)d_in[1];
    const float* whh0 = (const float*)d_in[2];
    const float* bih0 = (const float*)d_in[3];
    const float* bhh0 = (const float*)d_in[4];
    const float* wih1 = (const float*)d_in[5];
    const float* whh1 = (const float*)d_in[6];
    const float* bih1 = (const float*)d_in[7];
    const float* bhh1 = (const float*)d_in[8];
    const float* wih2 = (const float*)d_in[9];
    const float* whh2 = (const float*)d_in[10];
    const float* bih2 = (const float*)d_in[11];
    const float* bhh2 = (const float*)d_in[12];
    const float* fcw  = (const float*)d_in[13];
    const float* fcb  = (const float*)d_in[14];

    lstm3_mfma<<<dim3(NBATCH / NB), dim3(192), 0, stream>>>(
        x, wih0, whh0, bih0, bhh0,
        wih1, whh1, bih1, bhh1,
        wih2, whh2, bih2, bhh2,
        fcw, fcb, (float*)d_out);
}

// Round 14
// 703.821 us; speedup vs baseline: 2.3849x; 1.7231x over previous
//
#include <hip/hip_runtime.h>

typedef _Float16 half2v __attribute__((ext_vector_type(2)));

#define T_LEN 1024
#define NBATCH 1024
#define HID 20
#define G_B 2      // batch elements per wave (lane groups of 20)
#define STEPS 8    // timesteps per superstep (one barrier per STEPS steps)

#if defined(__has_builtin)
#if __has_builtin(__builtin_amdgcn_fdot2)
#define HAVE_FDOT2 1
#endif
#endif

#define NLOG2E  -1.4426950408889634f   // -log2(e):  sigmoid gates
#define N2LOG2E -2.8853900817779268f   // -2log2(e): tanh gates

__device__ __forceinline__ float fdot2_(half2v a, half2v b, float c) {
#ifdef HAVE_FDOT2
    return __builtin_amdgcn_fdot2(a, b, c, false);
#else
    return c + (float)a[0] * (float)b[0] + (float)a[1] * (float)b[1];
#endif
}

__device__ __forceinline__ half2v pack2(float a, float b) {
    half2v r; r[0] = (_Float16)a; r[1] = (_Float16)b; return r;
}

// p is the PRE-SCALED pre-gate: p = -log2e * z  ->  sigmoid(z)
__device__ __forceinline__ float sig2(float p) {
    return __builtin_amdgcn_rcpf(1.0f + __builtin_exp2f(p));
}
// p = -2log2e * z  ->  tanh(z)
__device__ __forceinline__ float tanh2(float p) {
    return 2.0f * __builtin_amdgcn_rcpf(1.0f + __builtin_exp2f(p)) - 1.0f;
}

// Load 20 f16 (one 24-half / 48B row, 16B-aligned) into 10 half2.
__device__ __forceinline__ void load_h20(const _Float16* row, half2v hp[10]) {
    uint4 q0 = *(const uint4*)(row);
    uint4 q1 = *(const uint4*)(row + 8);
    uint2 q2 = *(const uint2*)(row + 16);
    hp[0] = __builtin_bit_cast(half2v, q0.x);
    hp[1] = __builtin_bit_cast(half2v, q0.y);
    hp[2] = __builtin_bit_cast(half2v, q0.z);
    hp[3] = __builtin_bit_cast(half2v, q0.w);
    hp[4] = __builtin_bit_cast(half2v, q1.x);
    hp[5] = __builtin_bit_cast(half2v, q1.y);
    hp[6] = __builtin_bit_cast(half2v, q1.z);
    hp[7] = __builtin_bit_cast(half2v, q1.w);
    hp[8] = __builtin_bit_cast(half2v, q2.x);
    hp[9] = __builtin_bit_cast(half2v, q2.y);
}

// 20-element dot, two independent depth-5 chains, seeded with `seed`.
__device__ __forceinline__ float dot20s(const half2v W[10], const half2v h[10],
                                        float seed) {
    float a0 = seed, a1 = 0.f;
#pragma unroll
    for (int k = 0; k < 5; ++k) {
        a0 = fdot2_(W[k],     h[k],     a0);
        a1 = fdot2_(W[k + 5], h[k + 5], a1);
    }
    return a0 + a1;
}

// R10 structure (best measured: 843 us) + fast-rcp activations, ln2-folded
// weights, STEPS=8. Layer-pipelined 3-wave block, 2 batches/wave, 4 gates/
// lane, 8 steps/barrier, depth-16 LDS ring (slot = t & 15). Below-rows +
// ih-dots hoisted; own-h dots right after each h write (same-wave in-order
// DS readback). Weight rows/bias/wx pre-scaled by -log2e (i,f,o) or -2log2e
// (g) so activation = rcp(1+exp2(pre)) with no per-step multiply.
// Lane = g*20 + j; lanes 40..63 ride along, never write.
__global__ void __launch_bounds__(192, 2) lstm3_r14(
    const float* __restrict__ x,
    const float* __restrict__ wih0, const float* __restrict__ whh0,
    const float* __restrict__ bih0, const float* __restrict__ bhh0,
    const float* __restrict__ wih1, const float* __restrict__ whh1,
    const float* __restrict__ bih1, const float* __restrict__ bhh1,
    const float* __restrict__ wih2, const float* __restrict__ whh2,
    const float* __restrict__ bih2, const float* __restrict__ bhh2,
    const float* __restrict__ fcw, const float* __restrict__ fcb,
    float* __restrict__ out)
{
    __shared__ __align__(16) float xlds[G_B * T_LEN];         // interleaved [t][g]
    __shared__ __align__(16) _Float16 rings[3][16][G_B * 24]; // depth-16 rings

    const int tid = threadIdx.x;
    const int wv = tid / 64;
    const int lane = tid & 63;
    const long b_base = (long)blockIdx.x * G_B;

    {
        // stage x interleaved: xlds[2*t + g] = x[b_base+g][t]
        const float* xg = x + b_base * T_LEN;
        for (int i = tid; i < G_B * T_LEN; i += 192) {
            const int t = i & (T_LEN - 1);
            const int g = i >> 10;
            xlds[2 * t + g] = xg[i];
        }
        for (int i = tid; i < 3 * 16 * G_B * 24; i += 192)
            ((_Float16*)rings)[i] = (_Float16)0.0f;
    }

    const bool act = lane < G_B * HID;
    const int g = act ? (lane / HID) : 0;
    const int j = act ? (lane % HID) : 0;

    const float* whh = (wv == 0) ? whh0 : (wv == 1) ? whh1 : whh2;
    const float* wih = (wv == 0) ? wih0 : (wv == 1) ? wih1 : wih2;
    const float* bih = (wv == 0) ? bih0 : (wv == 1) ? bih1 : bih2;
    const float* bhh = (wv == 0) ? bhh0 : (wv == 1) ? bhh1 : bhh2;

    // All 4 gate rows (i,f,g,o) of unit j in VGPRs, pre-scaled by the
    // activation's log2 factor (i,f,o: -log2e; g: -2log2e).
    half2v Whh[4][10];
    half2v Wih[4][10];   // waves 1,2
    float bias[4];
    float wx[4] = {0.f, 0.f, 0.f, 0.f};
#pragma unroll
    for (int gt = 0; gt < 4; ++gt) {
        const float sc = (gt == 2) ? N2LOG2E : NLOG2E;
        const int r = gt * HID + j;
#pragma unroll
        for (int k4 = 0; k4 < 5; ++k4) {
            float4 v = *(const float4*)(whh + r * HID + 4 * k4);
            Whh[gt][2 * k4]     = pack2(sc * v.x, sc * v.y);
            Whh[gt][2 * k4 + 1] = pack2(sc * v.z, sc * v.w);
        }
        bias[gt] = sc * (bih[r] + bhh[r]);
        if (wv == 0) {
            wx[gt] = sc * wih[r];  // w_ih0 is (80,1)
        } else {
#pragma unroll
            for (int k4 = 0; k4 < 5; ++k4) {
                float4 v = *(const float4*)(wih + r * HID + 4 * k4);
                Wih[gt][2 * k4]     = pack2(sc * v.x, sc * v.y);
                Wih[gt][2 * k4 + 1] = pack2(sc * v.z, sc * v.w);
            }
        }
    }

    _Float16* const own_base = &rings[wv][0][0];
    const _Float16* const bel_base = (wv > 0) ? &rings[wv - 1][0][0]
                                              : &rings[0][0][0];

    float c = 0.0f;                              // cell state (own unit)
    float oA[4] = {0.f, 0.f, 0.f, 0.f};          // own-h partials (h(-1)=0)

    __syncthreads();

    const int SS = T_LEN / STEPS;  // supersteps per wave
    const int ROW = G_B * 24;      // halfs per timestep slot

    for (int s = 0; s < SS + 2; ++s) {
        const int m = s - wv;
        if (m >= 0 && m < SS) {
            const int qb = (m & 1) * (STEPS * ROW) + g * 24;  // octet base
            const int t0 = STEPS * m;

            // ---- hoisted pre-gates for ALL 8 steps ----
            float pre[STEPS][4];
            if (wv == 0) {
#pragma unroll
                for (int i = 0; i < STEPS; ++i) {
                    const float xt = xlds[2 * (t0 + i) + g];
#pragma unroll
                    for (int gt = 0; gt < 4; ++gt)
                        pre[i][gt] = bias[gt] + wx[gt] * xt;
                }
            } else {
#pragma unroll
                for (int i = 0; i < STEPS; ++i) {
                    half2v hb[10];
                    load_h20(bel_base + qb + i * ROW, hb);
#pragma unroll
                    for (int gt = 0; gt < 4; ++gt)
                        pre[i][gt] = dot20s(Wih[gt], hb, bias[gt]);
                }
            }
#pragma unroll
            for (int gt = 0; gt < 4; ++gt) pre[0][gt] += oA[gt];

            // ---- serial chain: 8 steps ----
#pragma unroll
            for (int i = 0; i < STEPS; ++i) {
                const float si = sig2(pre[i][0]);
                const float sf = sig2(pre[i][1]);
                const float tg = tanh2(pre[i][2]);
                const float so = sig2(pre[i][3]);
                c = sf * c + si * tg;
                const float hn = so * tanh2(N2LOG2E * c);
                _Float16* const wp = own_base + qb + i * ROW;
                if (act) wp[j] = (_Float16)hn;
                // own-h readback + dots (same-wave in-order DS, no sync)
                half2v ho[10];
                load_h20(wp, ho);
                if (i < STEPS - 1) {
#pragma unroll
                    for (int gt = 0; gt < 4; ++gt)
                        pre[i + 1][gt] = dot20s(Whh[gt], ho, pre[i + 1][gt]);
                } else {
#pragma unroll
                    for (int gt = 0; gt < 4; ++gt)
                        oA[gt] = dot20s(Whh[gt], ho, 0.0f);
                }
            }
        }
        __syncthreads();  // publish this superstep's 8 rows to the wave above
    }

    // FC epilogue: h2(T-1), slot (T_LEN-1)&15 = 15
    if (wv == 2 && lane < 2 * G_B) {
        const int gg = lane >> 1, o = lane & 1;
        float acc = fcb[o];
        const _Float16* h2 = &rings[2][15][gg * 24];
#pragma unroll
        for (int k = 0; k < HID; ++k) {
            acc += fcw[o * HID + k] * (float)h2[k];
        }
        out[(b_base + gg) * 2 + o] = acc;
    }
}

extern "C" void kernel_launch(void* const* d_in, const int* in_sizes, int n_in,
                              void* d_out, int out_size, void* d_ws, size_t ws_size,
                              hipStream_t stream) {
    const float* x    = (const float*)d_in[0];
    const float* wih0 = (const float*)d_in[1];
    const float* whh0 = (const float*)d_in[2];
    const float* bih0 = (const float*)d_in[3];
    const float* bhh0 = (const float*)d_in[4];
    const float* wih1 = (const float*)d_in[5];
    const float* whh1 = (const float*)d_in[6];
    const float* bih1 = (const float*)d_in[7];
    const float* bhh1 = (const float*)d_in[8];
    const float* wih2 = (const float*)d_in[9];
    const float* whh2 = (const float*)d_in[10];
    const float* bih2 = (const float*)d_in[11];
    const float* bhh2 = (const float*)d_in[12];
    const float* fcw  = (const float*)d_in[13];
    const float* fcb  = (const float*)d_in[14];

    lstm3_r14<<<dim3(NBATCH / G_B), dim3(192), 0, stream>>>(
        x, wih0, whh0, bih0, bhh0,
        wih1, whh1, bih1, bhh1,
        wih2, whh2, bih2, bhh2,
        fcw, fcb, (float*)d_out);
}

// Round 15
// 696.619 us; speedup vs baseline: 2.4096x; 1.0103x over previous
//
#include <hip/hip_runtime.h>

typedef _Float16 half2v __attribute__((ext_vector_type(2)));

#define T_LEN 1024
#define NBATCH 1024
#define HID 20
#define G_B 2      // batch elements per wave (lane groups of 20)
#define STEPS 8    // timesteps per superstep (one barrier per STEPS steps)

#if defined(__has_builtin)
#if __has_builtin(__builtin_amdgcn_fdot2)
#define HAVE_FDOT2 1
#endif
#endif

#define NLOG2E  -1.4426950408889634f   // -log2(e):  sigmoid gates
#define N2LOG2E -2.8853900817779268f   // -2log2(e): tanh gates

__device__ __forceinline__ float fdot2_(half2v a, half2v b, float c) {
#ifdef HAVE_FDOT2
    return __builtin_amdgcn_fdot2(a, b, c, false);
#else
    return c + (float)a[0] * (float)b[0] + (float)a[1] * (float)b[1];
#endif
}

__device__ __forceinline__ half2v pack2(float a, float b) {
    half2v r; r[0] = (_Float16)a; r[1] = (_Float16)b; return r;
}

// Load 20 f16 (one 24-half / 48B row, 16B-aligned) into 10 half2.
__device__ __forceinline__ void load_h20(const _Float16* row, half2v hp[10]) {
    uint4 q0 = *(const uint4*)(row);
    uint4 q1 = *(const uint4*)(row + 8);
    uint2 q2 = *(const uint2*)(row + 16);
    hp[0] = __builtin_bit_cast(half2v, q0.x);
    hp[1] = __builtin_bit_cast(half2v, q0.y);
    hp[2] = __builtin_bit_cast(half2v, q0.z);
    hp[3] = __builtin_bit_cast(half2v, q0.w);
    hp[4] = __builtin_bit_cast(half2v, q1.x);
    hp[5] = __builtin_bit_cast(half2v, q1.y);
    hp[6] = __builtin_bit_cast(half2v, q1.z);
    hp[7] = __builtin_bit_cast(half2v, q1.w);
    hp[8] = __builtin_bit_cast(half2v, q2.x);
    hp[9] = __builtin_bit_cast(half2v, q2.y);
}

// 20-element dot, two independent depth-5 chains, seeded with `seed`.
__device__ __forceinline__ float dot20s(const half2v W[10], const half2v h[10],
                                        float seed) {
    float a0 = seed, a1 = 0.f;
#pragma unroll
    for (int k = 0; k < 5; ++k) {
        a0 = fdot2_(W[k],     h[k],     a0);
        a1 = fdot2_(W[k + 5], h[k + 5], a1);
    }
    return a0 + a1;
}

// R14 structure (704 us) + shared-rcp activations (8 trans/batch-layer vs 10):
//   sigma(i)*tanh(g) = (1-e_g) * rcp((1+e_i)(1+e_g))
//   sigma(o)*tanh(c) = (1-e_c) * rcp((1+e_o)(1+e_c))
// Weights/bias/wx pre-scaled by -log2e (i,f,o) / -2log2e (g) at load so
// e = exp2(pre) directly. Layer-pipelined 3-wave block, 2 batches/wave,
// 4 gates/lane, 8 steps/barrier, depth-16 LDS ring. Below-rows + ih-dots
// hoisted; own-h dots right after each h write (same-wave in-order DS).
__global__ void __launch_bounds__(192, 2) lstm3_r15(
    const float* __restrict__ x,
    const float* __restrict__ wih0, const float* __restrict__ whh0,
    const float* __restrict__ bih0, const float* __restrict__ bhh0,
    const float* __restrict__ wih1, const float* __restrict__ whh1,
    const float* __restrict__ bih1, const float* __restrict__ bhh1,
    const float* __restrict__ wih2, const float* __restrict__ whh2,
    const float* __restrict__ bih2, const float* __restrict__ bhh2,
    const float* __restrict__ fcw, const float* __restrict__ fcb,
    float* __restrict__ out)
{
    __shared__ __align__(16) float xlds[G_B * T_LEN];         // interleaved [t][g]
    __shared__ __align__(16) _Float16 rings[3][16][G_B * 24]; // depth-16 rings

    const int tid = threadIdx.x;
    const int wv = tid / 64;
    const int lane = tid & 63;
    const long b_base = (long)blockIdx.x * G_B;

    {
        // stage x interleaved: xlds[2*t + g] = x[b_base+g][t]
        const float* xg = x + b_base * T_LEN;
        for (int i = tid; i < G_B * T_LEN; i += 192) {
            const int t = i & (T_LEN - 1);
            const int g = i >> 10;
            xlds[2 * t + g] = xg[i];
        }
        for (int i = tid; i < 3 * 16 * G_B * 24; i += 192)
            ((_Float16*)rings)[i] = (_Float16)0.0f;
    }

    const bool act = lane < G_B * HID;
    const int g = act ? (lane / HID) : 0;
    const int j = act ? (lane % HID) : 0;

    const float* whh = (wv == 0) ? whh0 : (wv == 1) ? whh1 : whh2;
    const float* wih = (wv == 0) ? wih0 : (wv == 1) ? wih1 : wih2;
    const float* bih = (wv == 0) ? bih0 : (wv == 1) ? bih1 : bih2;
    const float* bhh = (wv == 0) ? bhh0 : (wv == 1) ? bhh1 : bhh2;

    // All 4 gate rows (i,f,g,o) of unit j in VGPRs, pre-scaled by the
    // activation's log2 factor (i,f,o: -log2e; g: -2log2e).
    half2v Whh[4][10];
    half2v Wih[4][10];   // waves 1,2
    float bias[4];
    float wx[4] = {0.f, 0.f, 0.f, 0.f};
#pragma unroll
    for (int gt = 0; gt < 4; ++gt) {
        const float sc = (gt == 2) ? N2LOG2E : NLOG2E;
        const int r = gt * HID + j;
#pragma unroll
        for (int k4 = 0; k4 < 5; ++k4) {
            float4 v = *(const float4*)(whh + r * HID + 4 * k4);
            Whh[gt][2 * k4]     = pack2(sc * v.x, sc * v.y);
            Whh[gt][2 * k4 + 1] = pack2(sc * v.z, sc * v.w);
        }
        bias[gt] = sc * (bih[r] + bhh[r]);
        if (wv == 0) {
            wx[gt] = sc * wih[r];  // w_ih0 is (80,1)
        } else {
#pragma unroll
            for (int k4 = 0; k4 < 5; ++k4) {
                float4 v = *(const float4*)(wih + r * HID + 4 * k4);
                Wih[gt][2 * k4]     = pack2(sc * v.x, sc * v.y);
                Wih[gt][2 * k4 + 1] = pack2(sc * v.z, sc * v.w);
            }
        }
    }

    _Float16* const own_base = &rings[wv][0][0];
    const _Float16* const bel_base = (wv > 0) ? &rings[wv - 1][0][0]
                                              : &rings[0][0][0];

    float c = 0.0f;                              // cell state (own unit)
    // own-h partials for next superstep's step 0, bias-seeded (h(-1)=0)
    float oA[4] = {bias[0], bias[1], bias[2], bias[3]};

    __syncthreads();

    const int SS = T_LEN / STEPS;  // supersteps per wave
    const int ROW = G_B * 24;      // halfs per timestep slot

    for (int s = 0; s < SS + 2; ++s) {
        const int m = s - wv;
        if (m >= 0 && m < SS) {
            const int qb = (m & 1) * (STEPS * ROW) + g * 24;  // octet base
            const int t0 = STEPS * m;

            // ---- hoisted pre-gates for ALL 8 steps ----
            // step 0 starts from bias-seeded oA; steps 1..7 from bias.
            float pre[STEPS][4];
            if (wv == 0) {
                const float x0 = xlds[2 * t0 + g];
#pragma unroll
                for (int gt = 0; gt < 4; ++gt)
                    pre[0][gt] = oA[gt] + wx[gt] * x0;
#pragma unroll
                for (int i = 1; i < STEPS; ++i) {
                    const float xt = xlds[2 * (t0 + i) + g];
#pragma unroll
                    for (int gt = 0; gt < 4; ++gt)
                        pre[i][gt] = bias[gt] + wx[gt] * xt;
                }
            } else {
                {
                    half2v hb[10];
                    load_h20(bel_base + qb, hb);
#pragma unroll
                    for (int gt = 0; gt < 4; ++gt)
                        pre[0][gt] = dot20s(Wih[gt], hb, oA[gt]);
                }
#pragma unroll
                for (int i = 1; i < STEPS; ++i) {
                    half2v hb[10];
                    load_h20(bel_base + qb + i * ROW, hb);
#pragma unroll
                    for (int gt = 0; gt < 4; ++gt)
                        pre[i][gt] = dot20s(Wih[gt], hb, bias[gt]);
                }
            }

            // ---- serial chain: 8 steps, 8 trans each ----
#pragma unroll
            for (int i = 0; i < STEPS; ++i) {
                const float ei = __builtin_exp2f(pre[i][0]);
                const float ef = __builtin_exp2f(pre[i][1]);
                const float eg = __builtin_exp2f(pre[i][2]);
                const float eo = __builtin_exp2f(pre[i][3]);
                const float sf = __builtin_amdgcn_rcpf(1.0f + ef);
                const float u  = (1.0f - eg) *
                    __builtin_amdgcn_rcpf((1.0f + ei) * (1.0f + eg));
                c = sf * c + u;                       // sigma(f)*c + sigma(i)*tanh(g)
                const float ec = __builtin_exp2f(N2LOG2E * c);
                const float hn = (1.0f - ec) *
                    __builtin_amdgcn_rcpf((1.0f + eo) * (1.0f + ec));
                _Float16* const wp = own_base + qb + i * ROW;
                if (act) wp[j] = (_Float16)hn;
                // own-h readback + dots (same-wave in-order DS, no sync)
                half2v ho[10];
                load_h20(wp, ho);
                if (i < STEPS - 1) {
#pragma unroll
                    for (int gt = 0; gt < 4; ++gt)
                        pre[i + 1][gt] = dot20s(Whh[gt], ho, pre[i + 1][gt]);
                } else {
#pragma unroll
                    for (int gt = 0; gt < 4; ++gt)
                        oA[gt] = dot20s(Whh[gt], ho, bias[gt]);
                }
            }
        }
        __syncthreads();  // publish this superstep's 8 rows to the wave above
    }

    // FC epilogue: h2(T-1), slot (T_LEN-1)&15 = 15
    if (wv == 2 && lane < 2 * G_B) {
        const int gg = lane >> 1, o = lane & 1;
        float acc = fcb[o];
        const _Float16* h2 = &rings[2][15][gg * 24];
#pragma unroll
        for (int k = 0; k < HID; ++k) {
            acc += fcw[o * HID + k] * (float)h2[k];
        }
        out[(b_base + gg) * 2 + o] = acc;
    }
}

extern "C" void kernel_launch(void* const* d_in, const int* in_sizes, int n_in,
                              void* d_out, int out_size, void* d_ws, size_t ws_size,
                              hipStream_t stream) {
    const float* x    = (const float*)d_in[0];
    const float* wih0 = (const float*)d_in[1];
    const float* whh0 = (const float*)d_in[2];
    const float* bih0 = (const float*)d_in[3];
    const float* bhh0 = (const float*)d_in[4];
    const float* wih1 = (const float*)d_in[5];
    const float* whh1 = (const float*)d_in[6];
    const float* bih1 = (const float*)d_in[7];
    const float* bhh1 = (const float*)d_in[8];
    const float* wih2 = (const float*)d_in[9];
    const float* whh2 = (const float*)d_in[10];
    const float* bih2 = (const float*)d_in[11];
    const float* bhh2 = (const float*)d_in[12];
    const float* fcw  = (const float*)d_in[13];
    const float* fcb  = (const float*)d_in[14];

    lstm3_r15<<<dim3(NBATCH / G_B), dim3(192), 0, stream>>>(
        x, wih0, whh0, bih0, bhh0,
        wih1, whh1, bih1, bhh1,
        wih2, whh2, bih2, bhh2,
        fcw, fcb, (float*)d_out);
}